// Round 1
// baseline (27.513 us; speedup 1.0000x reference)
//
#include <hip/hip_runtime.h>

// out[t,j,i,f] = (i==j ? 0 : tanh( (w0+w1)*node[t,i,f] - w1*node[t,j,f]
//                                  + w2*edge[t,i,j,f] + b ))
// T=8, N=128, F=128. All float32.

__device__ __forceinline__ float fast_tanh(float x) {
    // tanh(x) = (e^{2x}-1)/(e^{2x}+1); clamp so __expf never overflows.
    x = fminf(fmaxf(x, -9.0f), 9.0f);
    float t = __expf(2.0f * x);
    return (t - 1.0f) / (t + 1.0f);
}

__global__ __launch_bounds__(256)
void EdgeUpdateNetwork_44555990729422_kernel(
    const float* __restrict__ node,   // (T,N,F)
    const float* __restrict__ edge,   // (T,N,N,F)
    const float* __restrict__ w,      // (3,)
    const float* __restrict__ b,      // (1,)
    float* __restrict__ out,          // (T,N,N,F) = swapaxes(e,1,2)
    int total_vec)                    // T*N*N*F/4
{
    const float w1  = w[1];
    const float w01 = w[0] + w1;
    const float w2  = w[2];
    const float bb  = b[0];

    const float4* __restrict__ edge4 = reinterpret_cast<const float4*>(edge);
    const float4* __restrict__ node4 = reinterpret_cast<const float4*>(node);
    float4* __restrict__ out4        = reinterpret_cast<float4*>(out);

    int idx    = blockIdx.x * blockDim.x + threadIdx.x;
    int stride = gridDim.x * blockDim.x;

    for (int v = idx; v < total_vec; v += stride) {
        // v ordered by OUT layout: (t, j, i, f4) with F/4 = 32 float4s per row
        int f4 = v & 31;
        int i  = (v >> 5)  & 127;
        int j  = (v >> 12) & 127;
        int t  = v >> 19;

        float4 e4 = edge4[(((t << 7) + i) << 7 | j) * 32 + f4];
        float4 ni = node4[((t << 7) + i) * 32 + f4];
        float4 nj = node4[((t << 7) + j) * 32 + f4];

        float m = (i == j) ? 0.0f : 1.0f;

        float4 r;
        r.x = m * fast_tanh(fmaf(w01, ni.x, fmaf(-w1, nj.x, fmaf(w2, e4.x, bb))));
        r.y = m * fast_tanh(fmaf(w01, ni.y, fmaf(-w1, nj.y, fmaf(w2, e4.y, bb))));
        r.z = m * fast_tanh(fmaf(w01, ni.z, fmaf(-w1, nj.z, fmaf(w2, e4.z, bb))));
        r.w = m * fast_tanh(fmaf(w01, ni.w, fmaf(-w1, nj.w, fmaf(w2, e4.w, bb))));

        out4[v] = r;
    }
}

extern "C" void kernel_launch(void* const* d_in, const int* in_sizes, int n_in,
                              void* d_out, int out_size, void* d_ws, size_t ws_size,
                              hipStream_t stream) {
    const float* node = (const float*)d_in[0];
    const float* edge = (const float*)d_in[1];
    const float* w    = (const float*)d_in[2];
    const float* b    = (const float*)d_in[3];
    float* out        = (float*)d_out;

    const int total_vec = out_size / 4;           // 8*128*128*128/4 = 4194304
    const int block = 256;
    int blocks = (total_vec + block - 1) / block; // 16384
    if (blocks > 2048) blocks = 2048;             // grid-stride the rest

    EdgeUpdateNetwork_44555990729422_kernel<<<blocks, block, 0, stream>>>(
        node, edge, w, b, out, total_vec);
}

// Round 3
// 26.227 us; speedup vs baseline: 1.0490x; 1.0490x over previous
//
#include <hip/hip_runtime.h>

// out[t,j,i,f] = (i==j ? 0 : tanh( (w0+w1)*node[t,i,f] - w1*node[t,j,f]
//                                  + w2*edge[t,i,j,f] + b ))
// T=8, N=128, F=128, float32.
//
// Strategy: 8x8 (i,j) tile per block, full F. Read edge streaming (4 KiB
// contiguous per step), compute tanh, transpose via 32 KiB LDS, write out
// streaming (4 KiB contiguous per step). Both HBM streams fully coalesced.

typedef float f32x4 __attribute__((ext_vector_type(4)));

__device__ __forceinline__ float fast_tanh(float x) {
    x = fminf(fmaxf(x, -9.0f), 9.0f);
    float t = __expf(2.0f * x);
    return (t - 1.0f) / (t + 1.0f);
}

__global__ __launch_bounds__(256)
void EdgeUpdateNetwork_44555990729422_kernel(
    const float* __restrict__ node,   // (T,N,F)
    const float* __restrict__ edge,   // (T,N,N,F)
    const float* __restrict__ w,      // (3,)
    const float* __restrict__ b,      // (1,)
    float* __restrict__ out)          // (T,N,N,F) swapped (1,2)
{
    __shared__ f32x4 tile[8 * 8 * 32];   // [dj][di][f4], 32 KiB

    const float w1  = w[1];
    const float w01 = w[0] + w1;
    const float w2  = w[2];
    const float bb  = b[0];

    const int blk = blockIdx.x;           // 2048 blocks: (t, ib, jb)
    const int jb  = blk & 15;
    const int ib  = (blk >> 4) & 15;
    const int t   = blk >> 8;
    const int i0  = ib << 3;
    const int j0  = jb << 3;

    const int tid = threadIdx.x;
    const int f4  = tid & 31;             // float4 index along F
    const int dq  = tid >> 5;             // 0..7: dj (read phase) / di (write phase)

    const f32x4* __restrict__ node4 = reinterpret_cast<const f32x4*>(node);
    const f32x4* __restrict__ edge4 = reinterpret_cast<const f32x4*>(edge);
    f32x4* __restrict__ out4        = reinterpret_cast<f32x4*>(out);

    // Hoisted per-thread constant: c = -w1 * node[t, j0+dq, f] + b
    f32x4 nj = node4[((t << 7) + j0 + dq) * 32 + f4];
    const float cx = fmaf(-w1, nj.x, bb);
    const float cy = fmaf(-w1, nj.y, bb);
    const float cz = fmaf(-w1, nj.z, bb);
    const float cw = fmaf(-w1, nj.w, bb);

    // Read phase: di = r, lanes cover (dj, f4). Edge reads are 4 KiB
    // contiguous per block per step.
    #pragma unroll
    for (int r = 0; r < 8; ++r) {
        const int i = i0 + r;
        f32x4 ni = node4[((t << 7) + i) * 32 + f4];
        f32x4 e  = edge4[(((t << 7) + i) * 128 + j0 + dq) * 32 + f4];
        const float m = (i == j0 + dq) ? 0.0f : 1.0f;
        f32x4 rv;
        rv.x = m * fast_tanh(fmaf(w01, ni.x, fmaf(w2, e.x, cx)));
        rv.y = m * fast_tanh(fmaf(w01, ni.y, fmaf(w2, e.y, cy)));
        rv.z = m * fast_tanh(fmaf(w01, ni.z, fmaf(w2, e.z, cz)));
        rv.w = m * fast_tanh(fmaf(w01, ni.w, fmaf(w2, e.w, cw)));
        tile[(dq * 8 + r) * 32 + f4] = rv;          // [dj][di][f4]
    }

    __syncthreads();

    // Write phase: dj = r, lanes cover (di, f4). Out writes are 4 KiB
    // contiguous per block per step.
    #pragma unroll
    for (int r = 0; r < 8; ++r) {
        f32x4 v = tile[(r * 8 + dq) * 32 + f4];
        const int j = j0 + r;
        __builtin_nontemporal_store(
            v, &out4[(((t << 7) + j) * 128 + i0 + dq) * 32 + f4]);
    }
}

extern "C" void kernel_launch(void* const* d_in, const int* in_sizes, int n_in,
                              void* d_out, int out_size, void* d_ws, size_t ws_size,
                              hipStream_t stream) {
    const float* node = (const float*)d_in[0];
    const float* edge = (const float*)d_in[1];
    const float* w    = (const float*)d_in[2];
    const float* b    = (const float*)d_in[3];
    float* out        = (float*)d_out;

    // T*(N/8)*(N/8) = 8*16*16 = 2048 blocks
    EdgeUpdateNetwork_44555990729422_kernel<<<2048, 256, 0, stream>>>(
        node, edge, w, b, out);
}

// Round 4
// 25.346 us; speedup vs baseline: 1.0855x; 1.0348x over previous
//
#include <hip/hip_runtime.h>

// out[t,j,i,f] = (i==j ? 0 : tanh( (w0+w1)*node[t,i,f] - w1*node[t,j,f]
//                                  + w2*edge[t,i,j,f] + b ))
// T=8, N=128, F=128, float32.
//
// R3: barrier-free, LDS-free. Each wave owns a 4(i) x 2(j) x F tile.
// Read phase: 4 x 1KiB contiguous edge loads per wave. Transpose is done
// in-register: the (i,j) swap only crosses the dq (lane>>5) boundary, so a
// single __shfl_xor(.,32) per write step exchanges the off-diagonal values.
// Write phase: 4 x 1KiB contiguous NT stores per wave. Zero LDS, zero
// __syncthreads -> occupancy capped only by VGPRs (launch_bounds forces <=64).

typedef float f32x4 __attribute__((ext_vector_type(4)));

__device__ __forceinline__ float fast_tanh(float x) {
    x = fminf(fmaxf(x, -9.0f), 9.0f);
    float t = __expf(2.0f * x);
    return (t - 1.0f) / (t + 1.0f);
}

__device__ __forceinline__ f32x4 shfl_xor32(f32x4 v) {
    f32x4 r;
    r.x = __shfl_xor(v.x, 32, 64);
    r.y = __shfl_xor(v.y, 32, 64);
    r.z = __shfl_xor(v.z, 32, 64);
    r.w = __shfl_xor(v.w, 32, 64);
    return r;
}

__global__ __launch_bounds__(256, 8)
void EdgeUpdateNetwork_44555990729422_kernel(
    const float* __restrict__ node,   // (T,N,F)
    const float* __restrict__ edge,   // (T,N,N,F)
    const float* __restrict__ w,      // (3,)
    const float* __restrict__ b,      // (1,)
    float* __restrict__ out)          // (T,N,N,F) swapped (1,2)
{
    const float w1  = w[1];
    const float w01 = w[0] + w1;
    const float w2  = w[2];
    const float bb  = b[0];

    // 4096 blocks: (t, ib:32, jb:16). Block tile = 4i x 8j x F.
    const int blk = blockIdx.x;
    const int jb  = blk & 15;
    const int ib  = (blk >> 4) & 31;
    const int t   = blk >> 9;
    const int i0  = ib << 2;
    const int j0  = jb << 3;

    const int tid  = threadIdx.x;
    const int wv   = tid >> 6;        // wave 0..3 -> j-pair within block
    const int lane = tid & 63;
    const int dq   = lane >> 5;       // 0/1
    const int f4   = lane & 31;

    const int jp = j0 + (wv << 1);    // wave's j-pair base
    const int jl = jp + dq;           // this thread's j (read phase)

    const f32x4* __restrict__ node4 = reinterpret_cast<const f32x4*>(node);
    const f32x4* __restrict__ edge4 = reinterpret_cast<const f32x4*>(edge);
    f32x4* __restrict__ out4        = reinterpret_cast<f32x4*>(out);

    // Hoisted: c = -w1 * node[t, jl, f] + b
    f32x4 nj = node4[(t * 128 + jl) * 32 + f4];
    f32x4 c  = (-w1) * nj + bb;

    // Read + compute: rv[r] = masked tanh for (i0+r, jl)
    f32x4 rv[4];
    #pragma unroll
    for (int r = 0; r < 4; ++r) {
        const int i = i0 + r;
        f32x4 ni = node4[(t * 128 + i) * 32 + f4];
        f32x4 e  = edge4[((t * 128 + i) * 128 + jl) * 32 + f4];
        f32x4 x  = w01 * ni + w2 * e + c;
        const float m = (i == jl) ? 0.0f : 1.0f;
        rv[r].x = m * fast_tanh(x.x);
        rv[r].y = m * fast_tanh(x.y);
        rv[r].z = m * fast_tanh(x.z);
        rv[r].w = m * fast_tanh(x.w);
    }

    // Write: step s covers i = i0+2s+dq for rows jp and jp+1.
    // dq=0 lacks (i0+2s, jp+1)   = partner's rv[2s]
    // dq=1 lacks (i0+2s+1, jp)   = partner's rv[2s+1]
    // -> one shfl_xor(32) per step: each half sends what the other needs.
    #pragma unroll
    for (int s = 0; s < 2; ++s) {
        const int iw = i0 + (s << 1) + dq;
        f32x4 send = (dq == 0) ? rv[2 * s + 1] : rv[2 * s];
        f32x4 recv = shfl_xor32(send);
        f32x4 v0 = (dq == 0) ? rv[2 * s] : recv;        // row jp
        f32x4 v1 = (dq == 0) ? recv : rv[2 * s + 1];    // row jp+1
        __builtin_nontemporal_store(v0, &out4[((t * 128 + jp    ) * 128 + iw) * 32 + f4]);
        __builtin_nontemporal_store(v1, &out4[((t * 128 + jp + 1) * 128 + iw) * 32 + f4]);
    }
}

extern "C" void kernel_launch(void* const* d_in, const int* in_sizes, int n_in,
                              void* d_out, int out_size, void* d_ws, size_t ws_size,
                              hipStream_t stream) {
    const float* node = (const float*)d_in[0];
    const float* edge = (const float*)d_in[1];
    const float* w    = (const float*)d_in[2];
    const float* b    = (const float*)d_in[3];
    float* out        = (float*)d_out;

    // T * (N/4) * (N/8) = 8*32*16 = 4096 blocks
    EdgeUpdateNetwork_44555990729422_kernel<<<4096, 256, 0, stream>>>(
        node, edge, w, b, out);
}